// Round 4
// baseline (351.578 us; speedup 1.0000x reference)
//
#include <hip/hip_runtime.h>
#include <math.h>

// Problem constants (from reference)
#define BB 4
#define NN 1024
#define EE 1024
#define HH 16
#define DD 64
#define MAXLEN 512
#define EPS 1e-5f

typedef __attribute__((ext_vector_type(8))) __bf16 bf16x8;
typedef __attribute__((ext_vector_type(4))) float floatx4;
typedef __attribute__((ext_vector_type(8))) unsigned short ushort8;

#define SWAIT(s) asm volatile("s_waitcnt " s ::: "memory")
#define SCHEDBAR() __builtin_amdgcn_sched_barrier(0)

__device__ __forceinline__ unsigned short f2bf(float f) {
    unsigned u = __float_as_uint(f);
    u += 0x7fffu + ((u >> 16) & 1u);   // RNE
    return (unsigned short)(u >> 16);
}

// counted vmcnt wait: rem = number of 4-load tile-groups allowed to remain
// in flight. Literal-string dispatch (s_waitcnt imm must be a literal).
template <int MAXR>
__device__ __forceinline__ void vm_wait_rt(int rem) {
    if (rem >= MAXR) {
        if constexpr (MAXR <= 0)      SWAIT("vmcnt(0)");
        else if constexpr (MAXR == 1) SWAIT("vmcnt(4)");
        else if constexpr (MAXR == 2) SWAIT("vmcnt(8)");
        else if constexpr (MAXR == 3) SWAIT("vmcnt(12)");
        else if constexpr (MAXR == 4) SWAIT("vmcnt(16)");
        else if constexpr (MAXR == 5) SWAIT("vmcnt(20)");
        else                          SWAIT("vmcnt(24)");
        return;
    }
    if (rem <= 0) { SWAIT("vmcnt(0)"); return; }
    if (rem == 1) { SWAIT("vmcnt(4)"); return; }
    if constexpr (MAXR >= 3) { if (rem == 2) { SWAIT("vmcnt(8)");  return; } }
    if constexpr (MAXR >= 4) { if (rem == 3) { SWAIT("vmcnt(12)"); return; } }
    if constexpr (MAXR >= 5) { if (rem == 4) { SWAIT("vmcnt(16)"); return; } }
    if constexpr (MAXR >= 6) { if (rem == 5) { SWAIT("vmcnt(20)"); return; } }
}

// ---------------------------------------------------------------------------
// fp32 -> bf16 conversion (vectorized by 4)
// ---------------------------------------------------------------------------
__global__ __launch_bounds__(256) void f2bf_kernel(const float* __restrict__ in,
                                                   unsigned short* __restrict__ out,
                                                   int n4) {
    int i = blockIdx.x * 256 + threadIdx.x;
    if (i < n4) {
        float4 v = ((const float4*)in)[i];
        ushort4 o;
        o.x = f2bf(v.x); o.y = f2bf(v.y); o.z = f2bf(v.z); o.w = f2bf(v.w);
        ((ushort4*)out)[i] = o;
    }
}

// ---------------------------------------------------------------------------
// LayerNorm: one block (256 threads) per row of E=1024; bf16 output.
// ---------------------------------------------------------------------------
__global__ __launch_bounds__(256) void ln_kernel(const float* __restrict__ x,
                                                 const float* __restrict__ g,
                                                 const float* __restrict__ b,
                                                 unsigned short* __restrict__ out) {
    const int row = blockIdx.x;
    const float* xr = x + (size_t)row * EE;
    float s = 0.f, s2 = 0.f;
    for (int j = threadIdx.x; j < EE; j += 256) {
        float v = xr[j];
        s += v; s2 += v * v;
    }
    for (int off = 32; off > 0; off >>= 1) {
        s  += __shfl_xor(s, off);
        s2 += __shfl_xor(s2, off);
    }
    __shared__ float red[8];
    const int wave = threadIdx.x >> 6, lane = threadIdx.x & 63;
    if (lane == 0) { red[wave] = s; red[4 + wave] = s2; }
    __syncthreads();
    s  = red[0] + red[1] + red[2] + red[3];
    s2 = red[4] + red[5] + red[6] + red[7];
    const float mu  = s * (1.0f / EE);
    const float var = s2 * (1.0f / EE) - mu * mu;
    const float inv = rsqrtf(var + EPS);
    unsigned short* orow = out + (size_t)row * EE;
    for (int j = threadIdx.x; j < EE; j += 256) {
        orow[j] = f2bf((xr[j] - mu) * inv * g[j] + b[j]);
    }
}

// ---------------------------------------------------------------------------
// Pipelined bf16 MFMA GEMM: C[M,Nc] = A[M,K] @ W[Nc,K]^T + bias (+res)
// Ring-DEPTH LDS buffers (BK=32), ONE barrier per K-tile, register prefetch
// of next tile's A-frags overlapping current tile's MFMA (counted lgkmcnt),
// counted vmcnt keeps DEPTH-2 tiles' staging in flight across barriers.
//
// Per K-tile t:
//   vm_wait(rem = min(NT-2-t, DEPTH-2)) -> tile t+1's loads done, rest fly
//   s_barrier          -> publish t+1 residency; seal WAR on buf[(t-1)&mask]
//   stage(t+DEPTH-1)   -> 4 global_load_lds into buf[(t-1)&mask]
//   issue bf[0..3](t), af(t+1)[0..MR)   (FIFO: [af(t) done earlier][bf01][bf23][afN])
//   lgkmcnt(MR+2)      -> af(t)+bf01 ready; bf23+afN outstanding
//   MFMA cols 0,1      (LDS drains bf23+afN under this)
//   lgkmcnt(MR)        -> bf23 ready; afN outstanding into next iter
//   MFMA cols 2,3
//
// LDS swizzle (both-sides, rule #21): physical 16B slot p of row r holds
// logical quad q = p ^ ((r&15)>>1 & 3). Staging pre-swizzles the GLOBAL
// source column; reads apply the same XOR -> bank-conflict-free (measured 0).
//
// XSWZ: bijective XCD chunk swizzle (T1). HW assigns original linear block
// i to XCD i%8; remap work so XCD k processes a CONTIGUOUS row-panel chunk
// (all cols) -> panel-sharing blocks co-resident on one XCD's L2.
//
// VARIANT: 0 = bias + bf16 out; 1 = bias + relu + bf16 out;
//          2 = f32 out = acc + bias + res   (res may alias Cout elementwise)
// Requires M%BM==0, Nc%BN==0, K%64==0, K/32 >= DEPTH-1, grid%8==0 if XSWZ.
// ---------------------------------------------------------------------------
template <int BM, int BN, int WMG, int WNG, int DEPTH, int VARIANT, bool XSWZ>
__global__ __launch_bounds__(WMG * WNG * 64, (WMG * WNG == 8) ? 2 : 1)
void gemm_pl_kernel(
    const unsigned short* __restrict__ A,
    const unsigned short* __restrict__ W,
    const float* __restrict__ bias,
    const float* res, void* Cout, int Nc, int K) {
    constexpr int NW  = WMG * WNG;
    constexpr int WTM = BM / WMG;     // wave tile M: 128 or 64
    constexpr int WTN = BN / WNG;     // wave tile N: 64
    constexpr int MR  = WTM / 16;     // 8 or 4
    constexpr int NR  = WTN / 16;     // 4
    static_assert(NR == 4, "NR must be 4");
    constexpr int SA = BM / (16 * NW);  // A stage-writes per wave = 2
    constexpr int SB = BN / (16 * NW);  // B stage-writes per wave = 2
    static_assert(SA == 2 && SB == 2, "stage count must be 2+2");
    static_assert((DEPTH & (DEPTH - 1)) == 0, "DEPTH must be pow2");
    constexpr int DMASK = DEPTH - 1;

    __shared__ unsigned short smem[DEPTH][(BM + BN) * 32];

    const int tid  = threadIdx.x;
    const int lane = tid & 63;
    const int wv   = tid >> 6;
    const int wm   = wv / WNG;
    const int wn   = wv % WNG;

    int bx = blockIdx.x, by = blockIdx.y;
    if (XSWZ) {
        const int gx  = gridDim.x;
        const int nwg = gx * gridDim.y;          // must be %8 == 0
        const int lin = by * gx + bx;
        const int sl  = (lin & 7) * (nwg >> 3) + (lin >> 3);
        bx = sl % gx; by = sl / gx;
    }
    const int row0 = by * BM;
    const int col0 = bx * BN;
    const int NT   = K >> 5;

    // staging: lane covers LDS row (lane>>2), slot (lane&3); source column is
    // inverse-swizzled so reads can XOR with the same pattern.
    const int srow = lane >> 2;
    const int sq   = ((lane & 3) ^ ((lane >> 3) & 3)) * 8;   // elems
    const unsigned short* Ag = A + (size_t)(row0 + srow) * K + sq;
    const unsigned short* Wg = W + (size_t)(col0 + srow) * K + sq;

    auto stage = [&](int t) {
        unsigned short* dst = &smem[t & DMASK][0];
#pragma unroll
        for (int s = 0; s < SA; ++s) {
            const int r = (wv + s * NW) * 16;
            __builtin_amdgcn_global_load_lds(
                (const __attribute__((address_space(1))) unsigned int*)(Ag + (size_t)r * K + t * 32),
                (__attribute__((address_space(3))) unsigned int*)(dst + r * 32), 16, 0, 0);
        }
#pragma unroll
        for (int s = 0; s < SB; ++s) {
            const int r = (wv + s * NW) * 16;
            __builtin_amdgcn_global_load_lds(
                (const __attribute__((address_space(1))) unsigned int*)(Wg + (size_t)r * K + t * 32),
                (__attribute__((address_space(3))) unsigned int*)(dst + (BM + r) * 32), 16, 0, 0);
        }
    };

    // fragment read addressing (swizzled)
    const int frow = lane & 15;
    const int quad = lane >> 4;
    const int rq   = (quad ^ ((frow >> 1) & 3)) * 8;          // elems
    const int abase = (wm * WTM + frow) * 32 + rq;
    const int bbase = (BM + wn * WTN + frow) * 32 + rq;

    floatx4 acc[MR][4];
#pragma unroll
    for (int m = 0; m < MR; ++m)
#pragma unroll
        for (int n = 0; n < 4; ++n) acc[m][n] = (floatx4){0.f, 0.f, 0.f, 0.f};

    bf16x8 afA[MR], afB[MR];

    // ---- prologue: stage tiles 0..DEPTH-2; publish tile 0; preload af(0) ----
#pragma unroll
    for (int pt = 0; pt < DEPTH - 1; ++pt) stage(pt);
    vm_wait_rt<DEPTH - 2>(DEPTH - 2);
    __builtin_amdgcn_s_barrier();
    SCHEDBAR();
#pragma unroll
    for (int m = 0; m < MR; ++m)
        afA[m] = *(const bf16x8*)(&smem[0][0] + abase + m * (16 * 32));

#define GEMM_BODY(T, AFC, AFN, TAIL)                                           \
    {                                                                          \
        const int t_ = (T);                                                    \
        if (!(TAIL)) vm_wait_rt<DEPTH - 2>(NT - 2 - t_);                       \
        __builtin_amdgcn_s_barrier();                                          \
        SCHEDBAR();                                                            \
        if (t_ + DEPTH - 1 < NT) stage(t_ + DEPTH - 1);                        \
        const unsigned short* buf_ = &smem[t_ & DMASK][0];                     \
        bf16x8 bfr0 = *(const bf16x8*)(buf_ + bbase);                          \
        bf16x8 bfr1 = *(const bf16x8*)(buf_ + bbase + 16 * 32);                \
        SCHEDBAR();                                                            \
        bf16x8 bfr2 = *(const bf16x8*)(buf_ + bbase + 32 * 32);                \
        bf16x8 bfr3 = *(const bf16x8*)(buf_ + bbase + 48 * 32);                \
        if (!(TAIL)) {                                                         \
            const unsigned short* nbuf_ = &smem[(t_ + 1) & DMASK][0];          \
            _Pragma("unroll")                                                  \
            for (int m = 0; m < MR; ++m)                                       \
                AFN[m] = *(const bf16x8*)(nbuf_ + abase + m * (16 * 32));      \
        }                                                                      \
        SCHEDBAR();                                                            \
        if (TAIL) { SWAIT("lgkmcnt(2)"); }                                     \
        else { if constexpr (MR == 8) SWAIT("lgkmcnt(10)");                    \
               else SWAIT("lgkmcnt(6)"); }                                     \
        SCHEDBAR();                                                            \
        __builtin_amdgcn_s_setprio(1);                                         \
        _Pragma("unroll")                                                      \
        for (int m = 0; m < MR; ++m) {                                         \
            acc[m][0] = __builtin_amdgcn_mfma_f32_16x16x32_bf16(               \
                AFC[m], bfr0, acc[m][0], 0, 0, 0);                             \
            acc[m][1] = __builtin_amdgcn_mfma_f32_16x16x32_bf16(               \
                AFC[m], bfr1, acc[m][1], 0, 0, 0);                             \
        }                                                                      \
        SCHEDBAR();                                                            \
        if (TAIL) { SWAIT("lgkmcnt(0)"); }                                     \
        else { if constexpr (MR == 8) SWAIT("lgkmcnt(8)");                     \
               else SWAIT("lgkmcnt(4)"); }                                     \
        SCHEDBAR();                                                            \
        _Pragma("unroll")                                                      \
        for (int m = 0; m < MR; ++m) {                                         \
            acc[m][2] = __builtin_amdgcn_mfma_f32_16x16x32_bf16(               \
                AFC[m], bfr2, acc[m][2], 0, 0, 0);                             \
            acc[m][3] = __builtin_amdgcn_mfma_f32_16x16x32_bf16(               \
                AFC[m], bfr3, acc[m][3], 0, 0, 0);                             \
        }                                                                      \
        __builtin_amdgcn_s_setprio(0);                                         \
        SCHEDBAR();                                                            \
    }

    // NT is even (K%64==0): 2x-unrolled loop keeps af indexing static.
    int t = 0;
    for (; t < NT - 2; t += 2) {
        GEMM_BODY(t,     afA, afB, false);
        GEMM_BODY(t + 1, afB, afA, false);
    }
    GEMM_BODY(NT - 2, afA, afB, false);
    GEMM_BODY(NT - 1, afB, afA, true);
#undef GEMM_BODY

    // ---- epilogue ----
    const int crow = (lane >> 4) * 4;
    const int ccol = lane & 15;
#pragma unroll
    for (int n = 0; n < 4; ++n) {
        const int nn = col0 + wn * WTN + n * 16 + ccol;
        const float bv = bias[nn];
#pragma unroll
        for (int m = 0; m < MR; ++m) {
#pragma unroll
            for (int r = 0; r < 4; ++r) {
                const int mm = row0 + wm * WTM + m * 16 + crow + r;
                float v = acc[m][n][r] + bv;
                if (VARIANT == 1) v = fmaxf(v, 0.f);
                if (VARIANT == 2) {
                    ((float*)Cout)[(size_t)mm * Nc + nn] = v + res[(size_t)mm * Nc + nn];
                } else {
                    ((unsigned short*)Cout)[(size_t)mm * Nc + nn] = f2bf(v);
                }
            }
        }
    }
}

// ---------------------------------------------------------------------------
// Flash-style MFMA attention. rel_bias(i,j) finite only for 0 <= i-j < 512
// (causal sliding window). One block = 64 Q rows for (b,h); 4 waves, each
// owns 16 Q rows. QK^T and PV via mfma_f32_16x16x32_bf16; online softmax.
// ---------------------------------------------------------------------------
__global__ __launch_bounds__(256) void attn_mfma_kernel(
    const unsigned short* __restrict__ qkv,
    const float* __restrict__ rel_pos,
    unsigned short* __restrict__ o) {
    __shared__ unsigned short K_s[2][64][32];     // 8 KB
    __shared__ unsigned short V_s[64][72];        // 9 KB  [d][key]
    __shared__ unsigned short P_s[4][2][16][32];  // 8 KB  per-wave
    __shared__ float rel_s[MAXLEN];               // 2 KB

    const int qt = blockIdx.x, h = blockIdx.y, b = blockIdx.z;
    const int q0 = qt * 64;
    const int tid  = threadIdx.x;
    const int lane = tid & 63;
    const int w    = tid >> 6;
    const int quad = lane >> 4;
    const int c15  = lane & 15;

    rel_s[tid]       = rel_pos[h * MAXLEN + tid];
    rel_s[tid + 256] = rel_pos[h * MAXLEN + tid + 256];

    const size_t rowstride = 3 * EE;
    const size_t base_q = (size_t)(b * NN) * rowstride + h * DD;
    const size_t base_k = base_q + EE;
    const size_t base_v = base_q + 2 * EE;

    bf16x8 aq[2];
    {
        const unsigned short* qrow =
            qkv + base_q + (size_t)(q0 + w * 16 + c15) * rowstride + quad * 8;
        aq[0] = *(const bf16x8*)(qrow);
        aq[1] = *(const bf16x8*)(qrow + 32);
    }

    floatx4 Oacc[4];
#pragma unroll
    for (int j = 0; j < 4; ++j) Oacc[j] = (floatx4){0.f, 0.f, 0.f, 0.f};
    float m_r[4], l_r[4];
#pragma unroll
    for (int r = 0; r < 4; ++r) { m_r[r] = -1e30f; l_r[r] = 0.f; }

    const int jlo = max(0, q0 - (MAXLEN - 1));
    const int c0 = jlo >> 6;
    const int c1 = (q0 + 63) >> 6;

    for (int cc = c0; cc <= c1; ++cc) {
        const int jb0 = cc << 6;
        __syncthreads();

        {
            const int krow = w * 16 + (lane >> 2);
            const int dofs = (lane & 3) * 8;
            const unsigned short* gk =
                qkv + base_k + (size_t)(jb0 + krow) * rowstride + dofs;
            __builtin_amdgcn_global_load_lds(
                (const __attribute__((address_space(1))) unsigned int*)gk,
                (__attribute__((address_space(3))) unsigned int*)&K_s[0][w * 16][0],
                16, 0, 0);
            __builtin_amdgcn_global_load_lds(
                (const __attribute__((address_space(1))) unsigned int*)(gk + 32),
                (__attribute__((address_space(3))) unsigned int*)&K_s[1][w * 16][0],
                16, 0, 0);
        }
        {
            const int key = lane;
            const int d0  = w * 16;
            const unsigned short* gv =
                qkv + base_v + (size_t)(jb0 + key) * rowstride + d0;
            ushort8 va = *(const ushort8*)(gv);
            ushort8 vb = *(const ushort8*)(gv + 8);
#pragma unroll
            for (int ii = 0; ii < 8; ++ii) V_s[d0 + ii][key] = va[ii];
#pragma unroll
            for (int ii = 0; ii < 8; ++ii) V_s[d0 + 8 + ii][key] = vb[ii];
        }
        __syncthreads();

        floatx4 S[4];
#pragma unroll
        for (int jb = 0; jb < 4; ++jb) {
            S[jb] = (floatx4){0.f, 0.f, 0.f, 0.f};
            bf16x8 bk0 = *(const bf16x8*)&K_s[0][jb * 16 + c15][quad * 8];
            bf16x8 bk1 = *(const bf16x8*)&K_s[1][jb * 16 + c15][quad * 8];
            S[jb] = __builtin_amdgcn_mfma_f32_16x16x32_bf16(aq[0], bk0, S[jb], 0, 0, 0);
            S[jb] = __builtin_amdgcn_mfma_f32_16x16x32_bf16(aq[1], bk1, S[jb], 0, 0, 0);
        }

        const int i_base = q0 + w * 16 + quad * 4;
        float sv[4][4];
        float mc[4] = {-1e30f, -1e30f, -1e30f, -1e30f};
#pragma unroll
        for (int jb = 0; jb < 4; ++jb) {
            const int jg = jb0 + jb * 16 + c15;
#pragma unroll
            for (int r = 0; r < 4; ++r) {
                const int rel = (i_base + r) - jg;
                float s;
                if (rel >= 0 && rel < MAXLEN) s = S[jb][r] * 0.125f + rel_s[rel];
                else                          s = -1e30f;
                sv[jb][r] = s;
                mc[r] = fmaxf(mc[r], s);
            }
        }
#pragma unroll
        for (int off = 1; off < 16; off <<= 1)
#pragma unroll
            for (int r = 0; r < 4; ++r) mc[r] = fmaxf(mc[r], __shfl_xor(mc[r], off));

        float alpha[4], psum[4];
#pragma unroll
        for (int r = 0; r < 4; ++r) {
            const float mn = fmaxf(m_r[r], mc[r]);
            alpha[r] = __expf(m_r[r] - mn);
            m_r[r] = mn;
            psum[r] = 0.f;
        }
#pragma unroll
        for (int jb = 0; jb < 4; ++jb)
#pragma unroll
            for (int r = 0; r < 4; ++r) {
                const float p = __expf(sv[jb][r] - m_r[r]);
                sv[jb][r] = p;
                psum[r] += p;
            }
#pragma unroll
        for (int off = 1; off < 16; off <<= 1)
#pragma unroll
            for (int r = 0; r < 4; ++r) psum[r] += __shfl_xor(psum[r], off);
#pragma unroll
        for (int r = 0; r < 4; ++r) l_r[r] = l_r[r] * alpha[r] + psum[r];
#pragma unroll
        for (int jb = 0; jb < 4; ++jb)
#pragma unroll
            for (int r = 0; r < 4; ++r) Oacc[jb][r] *= alpha[r];

#pragma unroll
        for (int jb = 0; jb < 4; ++jb)
#pragma unroll
            for (int r = 0; r < 4; ++r)
                P_s[w][jb >> 1][quad * 4 + r][(jb & 1) * 16 + c15] = f2bf(sv[jb][r]);

        bf16x8 ap0 = *(const bf16x8*)&P_s[w][0][c15][quad * 8];
        bf16x8 ap1 = *(const bf16x8*)&P_s[w][1][c15][quad * 8];

#pragma unroll
        for (int jd = 0; jd < 4; ++jd) {
            bf16x8 bv0 = *(const bf16x8*)&V_s[jd * 16 + c15][quad * 8];
            bf16x8 bv1 = *(const bf16x8*)&V_s[jd * 16 + c15][32 + quad * 8];
            Oacc[jd] = __builtin_amdgcn_mfma_f32_16x16x32_bf16(ap0, bv0, Oacc[jd], 0, 0, 0);
            Oacc[jd] = __builtin_amdgcn_mfma_f32_16x16x32_bf16(ap1, bv1, Oacc[jd], 0, 0, 0);
        }
    }

    float inv[4];
#pragma unroll
    for (int r = 0; r < 4; ++r) inv[r] = 1.0f / l_r[r];
#pragma unroll
    for (int jd = 0; jd < 4; ++jd) {
#pragma unroll
        for (int r = 0; r < 4; ++r) {
            const int row = q0 + w * 16 + quad * 4 + r;
            const int col = h * DD + jd * 16 + c15;
            o[(size_t)(b * NN + row) * EE + col] = f2bf(Oacc[jd][r] * inv[r]);
        }
    }
}

// ---------------------------------------------------------------------------
// Launch
// ---------------------------------------------------------------------------
extern "C" void kernel_launch(void* const* d_in, const int* in_sizes, int n_in,
                              void* d_out, int out_size, void* d_ws, size_t ws_size,
                              hipStream_t stream) {
    const float* x         = (const float*)d_in[0];
    const float* rel_pos   = (const float*)d_in[1];
    const float* in_proj_w = (const float*)d_in[2];
    const float* in_proj_b = (const float*)d_in[3];
    const float* out_w     = (const float*)d_in[4];
    const float* out_b     = (const float*)d_in[5];
    const float* w1        = (const float*)d_in[6];
    const float* b1        = (const float*)d_in[7];
    const float* w2        = (const float*)d_in[8];
    const float* b2        = (const float*)d_in[9];
    const float* ln1_g     = (const float*)d_in[10];
    const float* ln1_b     = (const float*)d_in[11];
    const float* ln2_g     = (const float*)d_in[12];
    const float* ln2_b     = (const float*)d_in[13];
    float* out = (float*)d_out;

    char* wsb = (char*)d_ws;
    const size_t MB = 1024 * 1024;
    unsigned short* wqkv_b = (unsigned short*)(wsb + 0);        // 6 MB
    unsigned short* wout_b = (unsigned short*)(wsb + 6 * MB);   // 2 MB
    unsigned short* w1_b   = (unsigned short*)(wsb + 8 * MB);   // 8 MB
    unsigned short* w2_b   = (unsigned short*)(wsb + 16 * MB);  // 8 MB
    unsigned short* xn_b   = (unsigned short*)(wsb + 24 * MB);  // 8 MB (xn, then xm)
    unsigned short* qkv_b  = (unsigned short*)(wsb + 32 * MB);  // 24 MB
    unsigned short* h_b    = (unsigned short*)(wsb + 32 * MB);  // 32 MB (reuses qkv+o)
    unsigned short* o_b    = (unsigned short*)(wsb + 56 * MB);  // 8 MB

    const int Mrows = BB * NN;   // 4096

    f2bf_kernel<<<(3 * EE * EE / 4 + 255) / 256, 256, 0, stream>>>(in_proj_w, wqkv_b, 3 * EE * EE / 4);
    f2bf_kernel<<<(EE * EE / 4 + 255) / 256, 256, 0, stream>>>(out_w, wout_b, EE * EE / 4);
    f2bf_kernel<<<(4 * EE * EE / 4 + 255) / 256, 256, 0, stream>>>(w1, w1_b, 4 * EE * EE / 4);
    f2bf_kernel<<<(4 * EE * EE / 4 + 255) / 256, 256, 0, stream>>>(w2, w2_b, 4 * EE * EE / 4);

    ln_kernel<<<Mrows, 256, 0, stream>>>(x, ln1_g, ln1_b, xn_b);
    // QKV: 256x256, ring-4, grid 12x16 = 192 blocks, XCD-swizzled
    gemm_pl_kernel<256, 256, 2, 4, 4, 0, true><<<dim3(3 * EE / 256, Mrows / 256), 512, 0, stream>>>(
        xn_b, wqkv_b, in_proj_b, nullptr, qkv_b, 3 * EE, EE);
    attn_mfma_kernel<<<dim3(NN / 64, HH, BB), 256, 0, stream>>>(qkv_b, rel_pos, o_b);
    // out-proj + residual: 128x128, ring-8 (deep prefetch), grid 8x32, XCD-swz
    gemm_pl_kernel<128, 128, 2, 2, 8, 2, true><<<dim3(EE / 128, Mrows / 128), 256, 0, stream>>>(
        o_b, wout_b, out_b, x, out, EE, EE);
    ln_kernel<<<Mrows, 256, 0, stream>>>(out, ln2_g, ln2_b, xn_b);
    // FFN1: 256x256, ring-4, grid 16x16 = 256 blocks, relu, XCD-swz
    gemm_pl_kernel<256, 256, 2, 4, 4, 1, true><<<dim3(4 * EE / 256, Mrows / 256), 512, 0, stream>>>(
        xn_b, w1_b, b1, nullptr, h_b, 4 * EE, EE);
    // FFN2 + residual (in-place on d_out): 128x128, ring-8, grid 8x32, XCD-swz
    gemm_pl_kernel<128, 128, 2, 2, 8, 2, true><<<dim3(EE / 128, Mrows / 128), 256, 0, stream>>>(
        h_b, w2_b, b2, out, out, EE, 4 * EE);
}

// Round 5
// 339.983 us; speedup vs baseline: 1.0341x; 1.0341x over previous
//
#include <hip/hip_runtime.h>
#include <math.h>

// Problem constants (from reference)
#define BB 4
#define NN 1024
#define EE 1024
#define HH 16
#define DD 64
#define MAXLEN 512
#define EPS 1e-5f

typedef __attribute__((ext_vector_type(8))) __bf16 bf16x8;
typedef __attribute__((ext_vector_type(4))) float floatx4;
typedef __attribute__((ext_vector_type(8))) unsigned short ushort8;

#define SWAIT(s) asm volatile("s_waitcnt " s ::: "memory")
#define SCHEDBAR() __builtin_amdgcn_sched_barrier(0)

__device__ __forceinline__ unsigned short f2bf(float f) {
    unsigned u = __float_as_uint(f);
    u += 0x7fffu + ((u >> 16) & 1u);   // RNE
    return (unsigned short)(u >> 16);
}

// counted vmcnt wait: rem = number of 4-load tile-groups allowed to remain
// in flight. Literal-string dispatch (s_waitcnt imm must be a literal).
template <int MAXR>
__device__ __forceinline__ void vm_wait_rt(int rem) {
    if (rem >= MAXR) {
        if constexpr (MAXR <= 0)      SWAIT("vmcnt(0)");
        else if constexpr (MAXR == 1) SWAIT("vmcnt(4)");
        else if constexpr (MAXR == 2) SWAIT("vmcnt(8)");
        else if constexpr (MAXR == 3) SWAIT("vmcnt(12)");
        else if constexpr (MAXR == 4) SWAIT("vmcnt(16)");
        else if constexpr (MAXR == 5) SWAIT("vmcnt(20)");
        else                          SWAIT("vmcnt(24)");
        return;
    }
    if (rem <= 0) { SWAIT("vmcnt(0)"); return; }
    if (rem == 1) { SWAIT("vmcnt(4)"); return; }
    if constexpr (MAXR >= 3) { if (rem == 2) { SWAIT("vmcnt(8)");  return; } }
    if constexpr (MAXR >= 4) { if (rem == 3) { SWAIT("vmcnt(12)"); return; } }
    if constexpr (MAXR >= 5) { if (rem == 4) { SWAIT("vmcnt(16)"); return; } }
    if constexpr (MAXR >= 6) { if (rem == 5) { SWAIT("vmcnt(20)"); return; } }
}

// ---------------------------------------------------------------------------
// fp32 -> bf16 conversion (vectorized by 4)
// ---------------------------------------------------------------------------
__global__ __launch_bounds__(256) void f2bf_kernel(const float* __restrict__ in,
                                                   unsigned short* __restrict__ out,
                                                   int n4) {
    int i = blockIdx.x * 256 + threadIdx.x;
    if (i < n4) {
        float4 v = ((const float4*)in)[i];
        ushort4 o;
        o.x = f2bf(v.x); o.y = f2bf(v.y); o.z = f2bf(v.z); o.w = f2bf(v.w);
        ((ushort4*)out)[i] = o;
    }
}

// ---------------------------------------------------------------------------
// LayerNorm: one block (256 threads) per row of E=1024; bf16 output.
// ---------------------------------------------------------------------------
__global__ __launch_bounds__(256) void ln_kernel(const float* __restrict__ x,
                                                 const float* __restrict__ g,
                                                 const float* __restrict__ b,
                                                 unsigned short* __restrict__ out) {
    const int row = blockIdx.x;
    const float* xr = x + (size_t)row * EE;
    float s = 0.f, s2 = 0.f;
    for (int j = threadIdx.x; j < EE; j += 256) {
        float v = xr[j];
        s += v; s2 += v * v;
    }
    for (int off = 32; off > 0; off >>= 1) {
        s  += __shfl_xor(s, off);
        s2 += __shfl_xor(s2, off);
    }
    __shared__ float red[8];
    const int wave = threadIdx.x >> 6, lane = threadIdx.x & 63;
    if (lane == 0) { red[wave] = s; red[4 + wave] = s2; }
    __syncthreads();
    s  = red[0] + red[1] + red[2] + red[3];
    s2 = red[4] + red[5] + red[6] + red[7];
    const float mu  = s * (1.0f / EE);
    const float var = s2 * (1.0f / EE) - mu * mu;
    const float inv = rsqrtf(var + EPS);
    unsigned short* orow = out + (size_t)row * EE;
    for (int j = threadIdx.x; j < EE; j += 256) {
        orow[j] = f2bf((xr[j] - mu) * inv * g[j] + b[j]);
    }
}

// ---------------------------------------------------------------------------
// Pipelined bf16 MFMA GEMM (256x256, 8 waves): C = A @ W^T + bias (relu)
// Ring-DEPTH LDS buffers (BK=32), ONE barrier per K-tile, register prefetch
// of next tile's A-frags overlapping current tile's MFMA (counted lgkmcnt),
// counted vmcnt keeps DEPTH-2 tiles' staging in flight across barriers.
// LDS swizzle: physical 16B slot p of row r holds logical quad p^((r&15)>>1&3);
// staging pre-swizzles the GLOBAL source column (rule #21 both-sides).
// XSWZ: bijective XCD chunk swizzle (grid must be %8==0).
// VARIANT: 0 = bias + bf16 out; 1 = bias + relu + bf16 out.
// ---------------------------------------------------------------------------
template <int BM, int BN, int WMG, int WNG, int DEPTH, int VARIANT, bool XSWZ>
__global__ __launch_bounds__(WMG * WNG * 64, (WMG * WNG == 8) ? 2 : 1)
void gemm_pl_kernel(
    const unsigned short* __restrict__ A,
    const unsigned short* __restrict__ W,
    const float* __restrict__ bias,
    const float* res, void* Cout, int Nc, int K) {
    constexpr int NW  = WMG * WNG;
    constexpr int WTM = BM / WMG;
    constexpr int WTN = BN / WNG;
    constexpr int MR  = WTM / 16;
    constexpr int NR  = WTN / 16;
    static_assert(NR == 4, "NR must be 4");
    constexpr int SA = BM / (16 * NW);
    constexpr int SB = BN / (16 * NW);
    static_assert(SA == 2 && SB == 2, "stage count must be 2+2");
    static_assert((DEPTH & (DEPTH - 1)) == 0, "DEPTH must be pow2");
    constexpr int DMASK = DEPTH - 1;

    __shared__ unsigned short smem[DEPTH][(BM + BN) * 32];

    const int tid  = threadIdx.x;
    const int lane = tid & 63;
    const int wv   = tid >> 6;
    const int wm   = wv / WNG;
    const int wn   = wv % WNG;

    int bx = blockIdx.x, by = blockIdx.y;
    if (XSWZ) {
        const int gx  = gridDim.x;
        const int nwg = gx * gridDim.y;
        const int lin = by * gx + bx;
        const int sl  = (lin & 7) * (nwg >> 3) + (lin >> 3);
        bx = sl % gx; by = sl / gx;
    }
    const int row0 = by * BM;
    const int col0 = bx * BN;
    const int NT   = K >> 5;

    const int srow = lane >> 2;
    const int sq   = ((lane & 3) ^ ((lane >> 3) & 3)) * 8;
    const unsigned short* Ag = A + (size_t)(row0 + srow) * K + sq;
    const unsigned short* Wg = W + (size_t)(col0 + srow) * K + sq;

    auto stage = [&](int t) {
        unsigned short* dst = &smem[t & DMASK][0];
#pragma unroll
        for (int s = 0; s < SA; ++s) {
            const int r = (wv + s * NW) * 16;
            __builtin_amdgcn_global_load_lds(
                (const __attribute__((address_space(1))) unsigned int*)(Ag + (size_t)r * K + t * 32),
                (__attribute__((address_space(3))) unsigned int*)(dst + r * 32), 16, 0, 0);
        }
#pragma unroll
        for (int s = 0; s < SB; ++s) {
            const int r = (wv + s * NW) * 16;
            __builtin_amdgcn_global_load_lds(
                (const __attribute__((address_space(1))) unsigned int*)(Wg + (size_t)r * K + t * 32),
                (__attribute__((address_space(3))) unsigned int*)(dst + (BM + r) * 32), 16, 0, 0);
        }
    };

    const int frow = lane & 15;
    const int quad = lane >> 4;
    const int rq   = (quad ^ ((frow >> 1) & 3)) * 8;
    const int abase = (wm * WTM + frow) * 32 + rq;
    const int bbase = (BM + wn * WTN + frow) * 32 + rq;

    floatx4 acc[MR][4];
#pragma unroll
    for (int m = 0; m < MR; ++m)
#pragma unroll
        for (int n = 0; n < 4; ++n) acc[m][n] = (floatx4){0.f, 0.f, 0.f, 0.f};

    bf16x8 afA[MR], afB[MR];

#pragma unroll
    for (int pt = 0; pt < DEPTH - 1; ++pt) stage(pt);
    vm_wait_rt<DEPTH - 2>(DEPTH - 2);
    __builtin_amdgcn_s_barrier();
    SCHEDBAR();
#pragma unroll
    for (int m = 0; m < MR; ++m)
        afA[m] = *(const bf16x8*)(&smem[0][0] + abase + m * (16 * 32));

#define GEMM_BODY(T, AFC, AFN, TAIL)                                           \
    {                                                                          \
        const int t_ = (T);                                                    \
        if (!(TAIL)) vm_wait_rt<DEPTH - 2>(NT - 2 - t_);                       \
        __builtin_amdgcn_s_barrier();                                          \
        SCHEDBAR();                                                            \
        if (t_ + DEPTH - 1 < NT) stage(t_ + DEPTH - 1);                        \
        const unsigned short* buf_ = &smem[t_ & DMASK][0];                     \
        bf16x8 bfr0 = *(const bf16x8*)(buf_ + bbase);                          \
        bf16x8 bfr1 = *(const bf16x8*)(buf_ + bbase + 16 * 32);                \
        SCHEDBAR();                                                            \
        bf16x8 bfr2 = *(const bf16x8*)(buf_ + bbase + 32 * 32);                \
        bf16x8 bfr3 = *(const bf16x8*)(buf_ + bbase + 48 * 32);                \
        if (!(TAIL)) {                                                         \
            const unsigned short* nbuf_ = &smem[(t_ + 1) & DMASK][0];          \
            _Pragma("unroll")                                                  \
            for (int m = 0; m < MR; ++m)                                       \
                AFN[m] = *(const bf16x8*)(nbuf_ + abase + m * (16 * 32));      \
        }                                                                      \
        SCHEDBAR();                                                            \
        if (TAIL) { SWAIT("lgkmcnt(2)"); }                                     \
        else { if constexpr (MR == 8) SWAIT("lgkmcnt(10)");                    \
               else SWAIT("lgkmcnt(6)"); }                                     \
        SCHEDBAR();                                                            \
        __builtin_amdgcn_s_setprio(1);                                         \
        _Pragma("unroll")                                                      \
        for (int m = 0; m < MR; ++m) {                                         \
            acc[m][0] = __builtin_amdgcn_mfma_f32_16x16x32_bf16(               \
                AFC[m], bfr0, acc[m][0], 0, 0, 0);                             \
            acc[m][1] = __builtin_amdgcn_mfma_f32_16x16x32_bf16(               \
                AFC[m], bfr1, acc[m][1], 0, 0, 0);                             \
        }                                                                      \
        SCHEDBAR();                                                            \
        if (TAIL) { SWAIT("lgkmcnt(0)"); }                                     \
        else { if constexpr (MR == 8) SWAIT("lgkmcnt(8)");                     \
               else SWAIT("lgkmcnt(4)"); }                                     \
        SCHEDBAR();                                                            \
        _Pragma("unroll")                                                      \
        for (int m = 0; m < MR; ++m) {                                         \
            acc[m][2] = __builtin_amdgcn_mfma_f32_16x16x32_bf16(               \
                AFC[m], bfr2, acc[m][2], 0, 0, 0);                             \
            acc[m][3] = __builtin_amdgcn_mfma_f32_16x16x32_bf16(               \
                AFC[m], bfr3, acc[m][3], 0, 0, 0);                             \
        }                                                                      \
        __builtin_amdgcn_s_setprio(0);                                         \
        SCHEDBAR();                                                            \
    }

    int t = 0;
    for (; t < NT - 2; t += 2) {
        GEMM_BODY(t,     afA, afB, false);
        GEMM_BODY(t + 1, afB, afA, false);
    }
    GEMM_BODY(NT - 2, afA, afB, false);
    GEMM_BODY(NT - 1, afB, afA, true);
#undef GEMM_BODY

    const int crow = (lane >> 4) * 4;
    const int ccol = lane & 15;
#pragma unroll
    for (int n = 0; n < 4; ++n) {
        const int nn = col0 + wn * WTN + n * 16 + ccol;
        const float bv = bias[nn];
#pragma unroll
        for (int m = 0; m < MR; ++m) {
#pragma unroll
            for (int r = 0; r < 4; ++r) {
                const int mm = row0 + wm * WTM + m * 16 + crow + r;
                float v = acc[m][n][r] + bv;
                if (VARIANT == 1) v = fmaxf(v, 0.f);
                if (VARIANT == 2) {
                    ((float*)Cout)[(size_t)mm * Nc + nn] = v + res[(size_t)mm * Nc + nn];
                } else {
                    ((unsigned short*)Cout)[(size_t)mm * Nc + nn] = f2bf(v);
                }
            }
        }
    }
}

// ---------------------------------------------------------------------------
// K-half GEMM for 128x128 tiles (grid-capped shapes): 8 waves as 2Mx2Nx2K.
// BM=BN=128, BK=64; each wave owns a 64x64 output and ONE K=32 half of the
// LDS tile (MR=4, NR=4, 16 MFMA + 8 ds_read_b128 per tile). Doubles waves/CU
// vs the 4-wave 128^2 config (grid = 256 = 1 block/CU is forced by shape) and
// halves the barrier count. wk=1 partials reduced into wk=0 via LDS at end.
// Ring-4 (128 KB), counted vmcnt (4 loads/tile), one s_barrier per K-tile,
// A-frag register prefetch with counted lgkmcnt.
// Row = 64 bf16 = 8 x 16B slots; physical slot p of row r holds logical slot
// p ^ (r&7); staging pre-swizzles global source column; reads XOR the same.
// (16-lane group covers all 32 banks 2-way -> conflict-free.)
// Output: f32 = acc + bias + res (res may alias Cout elementwise).
// Requires M%128==0, Nc%128==0, K%128==0, K/64 >= 4, grid%8==0.
// ---------------------------------------------------------------------------
__global__ __launch_bounds__(512, 2) void gemm_kh_kernel(
    const unsigned short* __restrict__ A,
    const unsigned short* __restrict__ W,
    const float* __restrict__ bias,
    const float* res, float* Cout, int Nc, int K) {
    __shared__ unsigned short smem[4][16384];   // 4 x (128+128) rows x 64 x 2B

    const int tid  = threadIdx.x;
    const int lane = tid & 63;
    const int wv   = tid >> 6;
    const int wk   = wv >> 2;          // K-half
    const int wm   = (wv >> 1) & 1;    // M-half
    const int wn   = wv & 1;           // N-half

    int bx = blockIdx.x, by = blockIdx.y;
    {   // bijective XCD chunk swizzle (grid %8 == 0)
        const int gx  = gridDim.x;
        const int nwg = gx * gridDim.y;
        const int lin = by * gx + bx;
        const int sl  = (lin & 7) * (nwg >> 3) + (lin >> 3);
        bx = sl % gx; by = sl / gx;
    }
    const int row0 = by * 128;
    const int col0 = bx * 128;
    const int NT   = K >> 6;

    // staging: lane covers row (lane>>3), physical slot (lane&7); global
    // source column inverse-swizzled: logical slot = (lane&7) ^ ((lane>>3)&7)
    const int srow = lane >> 3;
    const int sq   = ((lane & 7) ^ ((lane >> 3) & 7)) * 8;   // elems
    const unsigned short* Ag = A + (size_t)(row0 + srow) * K + sq;
    const unsigned short* Wg = W + (size_t)(col0 + srow) * K + sq;

    auto stage = [&](int t) {
        unsigned short* dst = &smem[t & 3][0];
#pragma unroll
        for (int s = 0; s < 2; ++s) {
            const int r = (wv + s * 8) * 8;     // 8-row chunk base
            __builtin_amdgcn_global_load_lds(
                (const __attribute__((address_space(1))) unsigned int*)(Ag + (size_t)r * K + t * 64),
                (__attribute__((address_space(3))) unsigned int*)(dst + r * 64), 16, 0, 0);
        }
#pragma unroll
        for (int s = 0; s < 2; ++s) {
            const int r = (wv + s * 8) * 8;
            __builtin_amdgcn_global_load_lds(
                (const __attribute__((address_space(1))) unsigned int*)(Wg + (size_t)r * K + t * 64),
                (__attribute__((address_space(3))) unsigned int*)(dst + 8192 + r * 64), 16, 0, 0);
        }
    };

    // fragment read addressing: logical slot = wk*4 + quad, phys = l ^ (frow&7)
    const int frow = lane & 15;
    const int quad = lane >> 4;
    const int phys = ((wk * 4 + quad) ^ (frow & 7)) * 8;     // elems
    const int abase = (wm * 64 + frow) * 64 + phys;
    const int bbase = 8192 + (wn * 64 + frow) * 64 + phys;

    floatx4 acc[4][4];
#pragma unroll
    for (int m = 0; m < 4; ++m)
#pragma unroll
        for (int n = 0; n < 4; ++n) acc[m][n] = (floatx4){0.f, 0.f, 0.f, 0.f};

    bf16x8 afA[4], afB[4];

    // prologue: stage tiles 0,1,2; publish tile 0; preload af(0)
    stage(0); stage(1); stage(2);
    SWAIT("vmcnt(8)");
    __builtin_amdgcn_s_barrier();
    SCHEDBAR();
#pragma unroll
    for (int m = 0; m < 4; ++m)
        afA[m] = *(const bf16x8*)(&smem[0][0] + abase + m * 1024);

#define KH_BODY(T, AFC, AFN, TAIL)                                             \
    {                                                                          \
        const int t_ = (T);                                                    \
        if (!(TAIL)) vm_wait_rt<2>(NT - 2 - t_);                               \
        __builtin_amdgcn_s_barrier();                                          \
        SCHEDBAR();                                                            \
        if (t_ + 3 < NT) stage(t_ + 3);                                        \
        const unsigned short* buf_ = &smem[t_ & 3][0];                         \
        bf16x8 bfr0 = *(const bf16x8*)(buf_ + bbase);                          \
        bf16x8 bfr1 = *(const bf16x8*)(buf_ + bbase + 1024);                   \
        SCHEDBAR();                                                            \
        bf16x8 bfr2 = *(const bf16x8*)(buf_ + bbase + 2048);                   \
        bf16x8 bfr3 = *(const bf16x8*)(buf_ + bbase + 3072);                   \
        if (!(TAIL)) {                                                         \
            const unsigned short* nbuf_ = &smem[(t_ + 1) & 3][0];              \
            _Pragma("unroll")                                                  \
            for (int m = 0; m < 4; ++m)                                        \
                AFN[m] = *(const bf16x8*)(nbuf_ + abase + m * 1024);           \
        }                                                                      \
        SCHEDBAR();                                                            \
        if (TAIL) { SWAIT("lgkmcnt(2)"); } else { SWAIT("lgkmcnt(6)"); }       \
        SCHEDBAR();                                                            \
        __builtin_amdgcn_s_setprio(1);                                         \
        _Pragma("unroll")                                                      \
        for (int m = 0; m < 4; ++m) {                                          \
            acc[m][0] = __builtin_amdgcn_mfma_f32_16x16x32_bf16(               \
                AFC[m], bfr0, acc[m][0], 0, 0, 0);                             \
            acc[m][1] = __builtin_amdgcn_mfma_f32_16x16x32_bf16(               \
                AFC[m], bfr1, acc[m][1], 0, 0, 0);                             \
        }                                                                      \
        SCHEDBAR();                                                            \
        if (TAIL) { SWAIT("lgkmcnt(0)"); } else { SWAIT("lgkmcnt(4)"); }       \
        SCHEDBAR();                                                            \
        _Pragma("unroll")                                                      \
        for (int m = 0; m < 4; ++m) {                                          \
            acc[m][2] = __builtin_amdgcn_mfma_f32_16x16x32_bf16(               \
                AFC[m], bfr2, acc[m][2], 0, 0, 0);                             \
            acc[m][3] = __builtin_amdgcn_mfma_f32_16x16x32_bf16(               \
                AFC[m], bfr3, acc[m][3], 0, 0, 0);                             \
        }                                                                      \
        __builtin_amdgcn_s_setprio(0);                                         \
        SCHEDBAR();                                                            \
    }

    int t = 0;
    for (; t < NT - 2; t += 2) {
        KH_BODY(t,     afA, afB, false);
        KH_BODY(t + 1, afB, afA, false);
    }
    KH_BODY(NT - 2, afA, afB, false);
    KH_BODY(NT - 1, afB, afA, true);
#undef KH_BODY

    // ---- cross-K reduction: wk=1 partials -> LDS -> wk=0 adds ----
    __syncthreads();
    float* pbuf = (float*)&smem[0][0];          // 4 pairs x 16 KB = 64 KB
    const int pair = wm * 2 + wn;
    if (wk == 1) {
#pragma unroll
        for (int m = 0; m < 4; ++m)
#pragma unroll
            for (int n = 0; n < 4; ++n)
                *(floatx4*)&pbuf[pair * 4096 + (m * 4 + n) * 256 + lane * 4] = acc[m][n];
    }
    __syncthreads();
    if (wk == 0) {
        const int crow = (lane >> 4) * 4;
        const int ccol = lane & 15;
#pragma unroll
        for (int n = 0; n < 4; ++n) {
            const int nn = col0 + wn * 64 + n * 16 + ccol;
            const float bv = bias[nn];
#pragma unroll
            for (int m = 0; m < 4; ++m) {
                floatx4 p = *(const floatx4*)&pbuf[pair * 4096 + (m * 4 + n) * 256 + lane * 4];
#pragma unroll
                for (int r = 0; r < 4; ++r) {
                    const int mm = row0 + wm * 64 + m * 16 + crow + r;
                    Cout[(size_t)mm * Nc + nn] =
                        acc[m][n][r] + p[r] + bv + res[(size_t)mm * Nc + nn];
                }
            }
        }
    }
}

// ---------------------------------------------------------------------------
// Flash-style MFMA attention. rel_bias(i,j) finite only for 0 <= i-j < 512
// (causal sliding window). One block = 64 Q rows for (b,h); 4 waves, each
// owns 16 Q rows. QK^T and PV via mfma_f32_16x16x32_bf16; online softmax.
// ---------------------------------------------------------------------------
__global__ __launch_bounds__(256) void attn_mfma_kernel(
    const unsigned short* __restrict__ qkv,
    const float* __restrict__ rel_pos,
    unsigned short* __restrict__ o) {
    __shared__ unsigned short K_s[2][64][32];     // 8 KB
    __shared__ unsigned short V_s[64][72];        // 9 KB  [d][key]
    __shared__ unsigned short P_s[4][2][16][32];  // 8 KB  per-wave
    __shared__ float rel_s[MAXLEN];               // 2 KB

    const int qt = blockIdx.x, h = blockIdx.y, b = blockIdx.z;
    const int q0 = qt * 64;
    const int tid  = threadIdx.x;
    const int lane = tid & 63;
    const int w    = tid >> 6;
    const int quad = lane >> 4;
    const int c15  = lane & 15;

    rel_s[tid]       = rel_pos[h * MAXLEN + tid];
    rel_s[tid + 256] = rel_pos[h * MAXLEN + tid + 256];

    const size_t rowstride = 3 * EE;
    const size_t base_q = (size_t)(b * NN) * rowstride + h * DD;
    const size_t base_k = base_q + EE;
    const size_t base_v = base_q + 2 * EE;

    bf16x8 aq[2];
    {
        const unsigned short* qrow =
            qkv + base_q + (size_t)(q0 + w * 16 + c15) * rowstride + quad * 8;
        aq[0] = *(const bf16x8*)(qrow);
        aq[1] = *(const bf16x8*)(qrow + 32);
    }

    floatx4 Oacc[4];
#pragma unroll
    for (int j = 0; j < 4; ++j) Oacc[j] = (floatx4){0.f, 0.f, 0.f, 0.f};
    float m_r[4], l_r[4];
#pragma unroll
    for (int r = 0; r < 4; ++r) { m_r[r] = -1e30f; l_r[r] = 0.f; }

    const int jlo = max(0, q0 - (MAXLEN - 1));
    const int c0 = jlo >> 6;
    const int c1 = (q0 + 63) >> 6;

    for (int cc = c0; cc <= c1; ++cc) {
        const int jb0 = cc << 6;
        __syncthreads();

        {
            const int krow = w * 16 + (lane >> 2);
            const int dofs = (lane & 3) * 8;
            const unsigned short* gk =
                qkv + base_k + (size_t)(jb0 + krow) * rowstride + dofs;
            __builtin_amdgcn_global_load_lds(
                (const __attribute__((address_space(1))) unsigned int*)gk,
                (__attribute__((address_space(3))) unsigned int*)&K_s[0][w * 16][0],
                16, 0, 0);
            __builtin_amdgcn_global_load_lds(
                (const __attribute__((address_space(1))) unsigned int*)(gk + 32),
                (__attribute__((address_space(3))) unsigned int*)&K_s[1][w * 16][0],
                16, 0, 0);
        }
        {
            const int key = lane;
            const int d0  = w * 16;
            const unsigned short* gv =
                qkv + base_v + (size_t)(jb0 + key) * rowstride + d0;
            ushort8 va = *(const ushort8*)(gv);
            ushort8 vb = *(const ushort8*)(gv + 8);
#pragma unroll
            for (int ii = 0; ii < 8; ++ii) V_s[d0 + ii][key] = va[ii];
#pragma unroll
            for (int ii = 0; ii < 8; ++ii) V_s[d0 + 8 + ii][key] = vb[ii];
        }
        __syncthreads();

        floatx4 S[4];
#pragma unroll
        for (int jb = 0; jb < 4; ++jb) {
            S[jb] = (floatx4){0.f, 0.f, 0.f, 0.f};
            bf16x8 bk0 = *(const bf16x8*)&K_s[0][jb * 16 + c15][quad * 8];
            bf16x8 bk1 = *(const bf16x8*)&K_s[1][jb * 16 + c15][quad * 8];
            S[jb] = __builtin_amdgcn_mfma_f32_16x16x32_bf16(aq[0], bk0, S[jb], 0, 0, 0);
            S[jb] = __builtin_amdgcn_mfma_f32_16x16x32_bf16(aq[1], bk1, S[jb], 0, 0, 0);
        }

        const int i_base = q0 + w * 16 + quad * 4;
        float sv[4][4];
        float mc[4] = {-1e30f, -1e30f, -1e30f, -1e30f};
#pragma unroll
        for (int jb = 0; jb < 4; ++jb) {
            const int jg = jb0 + jb * 16 + c15;
#pragma unroll
            for (int r = 0; r < 4; ++r) {
                const int rel = (i_base + r) - jg;
                float s;
                if (rel >= 0 && rel < MAXLEN) s = S[jb][r] * 0.125f + rel_s[rel];
                else                          s = -1e30f;
                sv[jb][r] = s;
                mc[r] = fmaxf(mc[r], s);
            }
        }
#pragma unroll
        for (int off = 1; off < 16; off <<= 1)
#pragma unroll
            for (int r = 0; r < 4; ++r) mc[r] = fmaxf(mc[r], __shfl_xor(mc[r], off));

        float alpha[4], psum[4];
#pragma unroll
        for (int r = 0; r < 4; ++r) {
            const float mn = fmaxf(m_r[r], mc[r]);
            alpha[r] = __expf(m_r[r] - mn);
            m_r[r] = mn;
            psum[r] = 0.f;
        }
#pragma unroll
        for (int jb = 0; jb < 4; ++jb)
#pragma unroll
            for (int r = 0; r < 4; ++r) {
                const float p = __expf(sv[jb][r] - m_r[r]);
                sv[jb][r] = p;
                psum[r] += p;
            }
#pragma unroll
        for (int off = 1; off < 16; off <<= 1)
#pragma unroll
            for (int r = 0; r < 4; ++r) psum[r] += __shfl_xor(psum[r], off);
#pragma unroll
        for (int r = 0; r < 4; ++r) l_r[r] = l_r[r] * alpha[r] + psum[r];
#pragma unroll
        for (int jb = 0; jb < 4; ++jb)
#pragma unroll
            for (int r = 0; r < 4; ++r) Oacc[jb][r] *= alpha[r];

#pragma unroll
        for (int jb = 0; jb < 4; ++jb)
#pragma unroll
            for (int r = 0; r < 4; ++r)
                P_s[w][jb >> 1][quad * 4 + r][(jb & 1) * 16 + c15] = f2bf(sv[jb][r]);

        bf16x8 ap0 = *(const bf16x8*)&P_s[w][0][c15][quad * 8];
        bf16x8 ap1 = *(const bf16x8*)&P_s[w][1][c15][quad * 8];

#pragma unroll
        for (int jd = 0; jd < 4; ++jd) {
            bf16x8 bv0 = *(const bf16x8*)&V_s[jd * 16 + c15][quad * 8];
            bf16x8 bv1 = *(const bf16x8*)&V_s[jd * 16 + c15][32 + quad * 8];
            Oacc[jd] = __builtin_amdgcn_mfma_f32_16x16x32_bf16(ap0, bv0, Oacc[jd], 0, 0, 0);
            Oacc[jd] = __builtin_amdgcn_mfma_f32_16x16x32_bf16(ap1, bv1, Oacc[jd], 0, 0, 0);
        }
    }

    float inv[4];
#pragma unroll
    for (int r = 0; r < 4; ++r) inv[r] = 1.0f / l_r[r];
#pragma unroll
    for (int jd = 0; jd < 4; ++jd) {
#pragma unroll
        for (int r = 0; r < 4; ++r) {
            const int row = q0 + w * 16 + quad * 4 + r;
            const int col = h * DD + jd * 16 + c15;
            o[(size_t)(b * NN + row) * EE + col] = f2bf(Oacc[jd][r] * inv[r]);
        }
    }
}

// ---------------------------------------------------------------------------
// Launch
// ---------------------------------------------------------------------------
extern "C" void kernel_launch(void* const* d_in, const int* in_sizes, int n_in,
                              void* d_out, int out_size, void* d_ws, size_t ws_size,
                              hipStream_t stream) {
    const float* x         = (const float*)d_in[0];
    const float* rel_pos   = (const float*)d_in[1];
    const float* in_proj_w = (const float*)d_in[2];
    const float* in_proj_b = (const float*)d_in[3];
    const float* out_w     = (const float*)d_in[4];
    const float* out_b     = (const float*)d_in[5];
    const float* w1        = (const float*)d_in[6];
    const float* b1        = (const float*)d_in[7];
    const float* w2        = (const float*)d_in[8];
    const float* b2        = (const float*)d_in[9];
    const float* ln1_g     = (const float*)d_in[10];
    const float* ln1_b     = (const float*)d_in[11];
    const float* ln2_g     = (const float*)d_in[12];
    const float* ln2_b     = (const float*)d_in[13];
    float* out = (float*)d_out;

    char* wsb = (char*)d_ws;
    const size_t MB = 1024 * 1024;
    unsigned short* wqkv_b = (unsigned short*)(wsb + 0);        // 6 MB
    unsigned short* wout_b = (unsigned short*)(wsb + 6 * MB);   // 2 MB
    unsigned short* w1_b   = (unsigned short*)(wsb + 8 * MB);   // 8 MB
    unsigned short* w2_b   = (unsigned short*)(wsb + 16 * MB);  // 8 MB
    unsigned short* xn_b   = (unsigned short*)(wsb + 24 * MB);  // 8 MB (xn, then xm)
    unsigned short* qkv_b  = (unsigned short*)(wsb + 32 * MB);  // 24 MB
    unsigned short* h_b    = (unsigned short*)(wsb + 32 * MB);  // 32 MB (reuses qkv+o)
    unsigned short* o_b    = (unsigned short*)(wsb + 56 * MB);  // 8 MB

    const int Mrows = BB * NN;   // 4096

    f2bf_kernel<<<(3 * EE * EE / 4 + 255) / 256, 256, 0, stream>>>(in_proj_w, wqkv_b, 3 * EE * EE / 4);
    f2bf_kernel<<<(EE * EE / 4 + 255) / 256, 256, 0, stream>>>(out_w, wout_b, EE * EE / 4);
    f2bf_kernel<<<(4 * EE * EE / 4 + 255) / 256, 256, 0, stream>>>(w1, w1_b, 4 * EE * EE / 4);
    f2bf_kernel<<<(4 * EE * EE / 4 + 255) / 256, 256, 0, stream>>>(w2, w2_b, 4 * EE * EE / 4);

    ln_kernel<<<Mrows, 256, 0, stream>>>(x, ln1_g, ln1_b, xn_b);
    // QKV: 256x256, ring-4, grid 12x16 = 192 blocks, XCD-swizzled
    gemm_pl_kernel<256, 256, 2, 4, 4, 0, true><<<dim3(3 * EE / 256, Mrows / 256), 512, 0, stream>>>(
        xn_b, wqkv_b, in_proj_b, nullptr, qkv_b, 3 * EE, EE);
    attn_mfma_kernel<<<dim3(NN / 64, HH, BB), 256, 0, stream>>>(qkv_b, rel_pos, o_b);
    // out-proj + residual: 128x128 K-half kernel, 8 waves, grid 8x32 = 256
    gemm_kh_kernel<<<dim3(EE / 128, Mrows / 128), 512, 0, stream>>>(
        o_b, wout_b, out_b, x, out, EE, EE);
    ln_kernel<<<Mrows, 256, 0, stream>>>(out, ln2_g, ln2_b, xn_b);
    // FFN1: 256x256, ring-4, grid 16x16 = 256 blocks, relu, XCD-swz
    gemm_pl_kernel<256, 256, 2, 4, 4, 1, true><<<dim3(4 * EE / 256, Mrows / 256), 512, 0, stream>>>(
        xn_b, w1_b, b1, nullptr, h_b, 4 * EE, EE);
    // FFN2 + residual (in-place on d_out): 128x128 K-half kernel, grid 8x32
    gemm_kh_kernel<<<dim3(EE / 128, Mrows / 128), 512, 0, stream>>>(
        h_b, w2_b, b2, out, out, EE, 4 * EE);
}

// Round 6
// 327.843 us; speedup vs baseline: 1.0724x; 1.0370x over previous
//
#include <hip/hip_runtime.h>
#include <math.h>

// Problem constants (from reference)
#define BB 4
#define NN 1024
#define EE 1024
#define HH 16
#define DD 64
#define MAXLEN 512
#define EPS 1e-5f

typedef __attribute__((ext_vector_type(8))) __bf16 bf16x8;
typedef __attribute__((ext_vector_type(4))) float floatx4;
typedef __attribute__((ext_vector_type(8))) unsigned short ushort8;

#define SWAIT(s) asm volatile("s_waitcnt " s ::: "memory")
#define SCHEDBAR() __builtin_amdgcn_sched_barrier(0)

__device__ __forceinline__ unsigned short f2bf(float f) {
    unsigned u = __float_as_uint(f);
    u += 0x7fffu + ((u >> 16) & 1u);   // RNE
    return (unsigned short)(u >> 16);
}

// counted vmcnt wait: rem = number of 4-load tile-groups allowed to remain
// in flight. Literal-string dispatch (s_waitcnt imm must be a literal).
template <int MAXR>
__device__ __forceinline__ void vm_wait_rt(int rem) {
    if (rem >= MAXR) {
        if constexpr (MAXR <= 0)      SWAIT("vmcnt(0)");
        else if constexpr (MAXR == 1) SWAIT("vmcnt(4)");
        else if constexpr (MAXR == 2) SWAIT("vmcnt(8)");
        else                          SWAIT("vmcnt(12)");
        return;
    }
    if (rem <= 0) { SWAIT("vmcnt(0)"); return; }
    if (rem == 1) { SWAIT("vmcnt(4)"); return; }
    if constexpr (MAXR >= 3) { if (rem == 2) { SWAIT("vmcnt(8)");  return; } }
}

// ---------------------------------------------------------------------------
// fp32 -> bf16 for all four weight matrices in ONE launch (4 segments).
// Segment sizes in float4 units: 3E^2/4, E^2/4, 4E^2/4, 4E^2/4.
// ---------------------------------------------------------------------------
__global__ __launch_bounds__(256) void f2bf_all_kernel(
    const float* __restrict__ s0, const float* __restrict__ s1,
    const float* __restrict__ s2, const float* __restrict__ s3,
    unsigned short* __restrict__ d0, unsigned short* __restrict__ d1,
    unsigned short* __restrict__ d2, unsigned short* __restrict__ d3) {
    const int C0 = 3 * EE * EE / 4;            // 786432
    const int C1 = C0 + EE * EE / 4;           // 1048576
    const int C2 = C1 + EE * EE;               // 2097152
    int i = blockIdx.x * 256 + threadIdx.x;
    const float* in; unsigned short* out; int j;
    if (i < C0)      { in = s0; out = d0; j = i; }
    else if (i < C1) { in = s1; out = d1; j = i - C0; }
    else if (i < C2) { in = s2; out = d2; j = i - C1; }
    else             { in = s3; out = d3; j = i - C2; }
    float4 v = ((const float4*)in)[j];
    ushort4 o;
    o.x = f2bf(v.x); o.y = f2bf(v.y); o.z = f2bf(v.z); o.w = f2bf(v.w);
    ((ushort4*)out)[j] = o;
}

// ---------------------------------------------------------------------------
// LayerNorm: one block per row of E=1024; float4 loads (1 per thread);
// bf16 ushort4 output.
// ---------------------------------------------------------------------------
__global__ __launch_bounds__(256) void ln_kernel(const float* __restrict__ x,
                                                 const float* __restrict__ g,
                                                 const float* __restrict__ b,
                                                 unsigned short* __restrict__ out) {
    const int row = blockIdx.x;
    const int tid = threadIdx.x;
    const float4 v = ((const float4*)(x + (size_t)row * EE))[tid];
    float s  = v.x + v.y + v.z + v.w;
    float s2 = v.x * v.x + v.y * v.y + v.z * v.z + v.w * v.w;
    for (int off = 32; off > 0; off >>= 1) {
        s  += __shfl_xor(s, off);
        s2 += __shfl_xor(s2, off);
    }
    __shared__ float red[8];
    const int wave = tid >> 6, lane = tid & 63;
    if (lane == 0) { red[wave] = s; red[4 + wave] = s2; }
    __syncthreads();
    s  = red[0] + red[1] + red[2] + red[3];
    s2 = red[4] + red[5] + red[6] + red[7];
    const float mu  = s * (1.0f / EE);
    const float var = s2 * (1.0f / EE) - mu * mu;
    const float inv = rsqrtf(var + EPS);
    const float4 gv = ((const float4*)g)[tid];
    const float4 bv = ((const float4*)b)[tid];
    ushort4 o;
    o.x = f2bf((v.x - mu) * inv * gv.x + bv.x);
    o.y = f2bf((v.y - mu) * inv * gv.y + bv.y);
    o.z = f2bf((v.z - mu) * inv * gv.z + bv.z);
    o.w = f2bf((v.w - mu) * inv * gv.w + bv.w);
    ((ushort4*)(out + (size_t)row * EE))[tid] = o;
}

// ---------------------------------------------------------------------------
// m97-style TLP GEMM: 128x128 tile, 4 waves (64x64 each), ring-2 BK=32
// buffers (32 KB LDS) -> 3 blocks/CU (12 waves) with VGPR<=170
// (__launch_bounds__(256,3)). Counted vmcnt(4) (never 0 mid-loop); tile t+2
// staged at the TAIL of body t (after trailing barrier: all reads of tile t
// drained block-wide -> WAR-safe overwrite of buf[t&1]). Compiler manages
// lgkmcnt for the ds_read->MFMA chain (proven fine-grained, m97).
// Both-sides swizzle: physical 16B slot p of row r holds logical quad
// p ^ ((r&15)>>1 & 3); staging pre-swizzles the GLOBAL source column.
// XCD chunk swizzle (grid %8 == 0).
// VARIANT: 0 = bias + bf16 out; 1 = bias + relu + bf16 out.
// Requires M%128==0, Nc%128==0, K%32==0, K/32 >= 2.
// ---------------------------------------------------------------------------
template <int VARIANT>
__global__ __launch_bounds__(256, 3) void gemm97t_kernel(
    const unsigned short* __restrict__ A,
    const unsigned short* __restrict__ W,
    const float* __restrict__ bias,
    void* __restrict__ Cout, int Nc, int K) {
    __shared__ unsigned short smem[2][8192];   // 2 x (128 A-rows + 128 B-rows) x 32

    const int tid  = threadIdx.x;
    const int lane = tid & 63;
    const int wv   = tid >> 6;          // 0..3
    const int wm   = wv >> 1;
    const int wn   = wv & 1;

    int bx = blockIdx.x, by = blockIdx.y;
    {   // bijective XCD chunk swizzle (grid %8 == 0)
        const int gx  = gridDim.x;
        const int nwg = gx * gridDim.y;
        const int lin = by * gx + bx;
        const int sl  = (lin & 7) * (nwg >> 3) + (lin >> 3);
        bx = sl % gx; by = sl / gx;
    }
    const int row0 = by * 128;
    const int col0 = bx * 128;
    const int NT   = K >> 5;

    // staging: lane covers row (lane>>2), phys slot (lane&3); global source
    // column inverse-swizzled so reads can XOR the same pattern.
    const int srow = lane >> 2;
    const int sq   = ((lane & 3) ^ ((lane >> 3) & 3)) * 8;   // elems
    const unsigned short* Ag = A + (size_t)(row0 + srow) * K + sq;
    const unsigned short* Wg = W + (size_t)(col0 + srow) * K + sq;

    auto stage = [&](int t) {
        unsigned short* dst = &smem[t & 1][0];
#pragma unroll
        for (int s = 0; s < 2; ++s) {
            const int r = (wv + s * 4) * 16;
            __builtin_amdgcn_global_load_lds(
                (const __attribute__((address_space(1))) unsigned int*)(Ag + (size_t)r * K + t * 32),
                (__attribute__((address_space(3))) unsigned int*)(dst + r * 32), 16, 0, 0);
        }
#pragma unroll
        for (int s = 0; s < 2; ++s) {
            const int r = (wv + s * 4) * 16;
            __builtin_amdgcn_global_load_lds(
                (const __attribute__((address_space(1))) unsigned int*)(Wg + (size_t)r * K + t * 32),
                (__attribute__((address_space(3))) unsigned int*)(dst + 4096 + r * 32), 16, 0, 0);
        }
    };

    // fragment read addressing (swizzled)
    const int frow = lane & 15;
    const int quad = lane >> 4;
    const int rq   = (quad ^ ((frow >> 1) & 3)) * 8;
    const int abase = (wm * 64 + frow) * 32 + rq;
    const int bbase = 4096 + (wn * 64 + frow) * 32 + rq;

    floatx4 acc[4][4];
#pragma unroll
    for (int m = 0; m < 4; ++m)
#pragma unroll
        for (int n = 0; n < 4; ++n) acc[m][n] = (floatx4){0.f, 0.f, 0.f, 0.f};

    // prologue: stage tiles 0 and 1 (8 loads/wave in flight)
    stage(0); stage(1);

    for (int t = 0; t < NT; ++t) {
        // drain tile t's 4 own loads (tile t+1's stay in flight); barrier
        // publishes residency block-wide (each wave staged distinct chunks).
        if (t == NT - 1) { SWAIT("vmcnt(0)"); } else { SWAIT("vmcnt(4)"); }
        __builtin_amdgcn_s_barrier();
        SCHEDBAR();

        const unsigned short* buf = &smem[t & 1][0];
        bf16x8 af0 = *(const bf16x8*)(buf + abase);
        bf16x8 af1 = *(const bf16x8*)(buf + abase + 512);
        bf16x8 af2 = *(const bf16x8*)(buf + abase + 1024);
        bf16x8 af3 = *(const bf16x8*)(buf + abase + 1536);
        bf16x8 bf0 = *(const bf16x8*)(buf + bbase);
        bf16x8 bf1 = *(const bf16x8*)(buf + bbase + 512);
        bf16x8 bf2 = *(const bf16x8*)(buf + bbase + 1024);
        bf16x8 bf3 = *(const bf16x8*)(buf + bbase + 1536);

        __builtin_amdgcn_s_setprio(1);
#pragma unroll
        for (int m = 0; m < 4; ++m)
            acc[m][0] = __builtin_amdgcn_mfma_f32_16x16x32_bf16(
                (m == 0 ? af0 : m == 1 ? af1 : m == 2 ? af2 : af3), bf0, acc[m][0], 0, 0, 0);
#pragma unroll
        for (int m = 0; m < 4; ++m)
            acc[m][1] = __builtin_amdgcn_mfma_f32_16x16x32_bf16(
                (m == 0 ? af0 : m == 1 ? af1 : m == 2 ? af2 : af3), bf1, acc[m][1], 0, 0, 0);
#pragma unroll
        for (int m = 0; m < 4; ++m)
            acc[m][2] = __builtin_amdgcn_mfma_f32_16x16x32_bf16(
                (m == 0 ? af0 : m == 1 ? af1 : m == 2 ? af2 : af3), bf2, acc[m][2], 0, 0, 0);
#pragma unroll
        for (int m = 0; m < 4; ++m)
            acc[m][3] = __builtin_amdgcn_mfma_f32_16x16x32_bf16(
                (m == 0 ? af0 : m == 1 ? af1 : m == 2 ? af2 : af3), bf3, acc[m][3], 0, 0, 0);
        __builtin_amdgcn_s_setprio(0);
        SCHEDBAR();
        // trailing barrier: all waves' reads of buf[t&1] complete -> safe to
        // overwrite with tile t+2. Loads get a full body (~1 tile) + next
        // head-wait of cover; 12-wave TLP hides the rest.
        __builtin_amdgcn_s_barrier();
        SCHEDBAR();
        if (t + 2 < NT) stage(t + 2);
        SCHEDBAR();
    }

    // epilogue
    unsigned short* Cb = (unsigned short*)Cout;
    const int crow = (lane >> 4) * 4;
    const int ccol = lane & 15;
#pragma unroll
    for (int n = 0; n < 4; ++n) {
        const int nn = col0 + wn * 64 + n * 16 + ccol;
        const float bv = bias[nn];
#pragma unroll
        for (int m = 0; m < 4; ++m) {
#pragma unroll
            for (int r = 0; r < 4; ++r) {
                const int mm = row0 + wm * 64 + m * 16 + crow + r;
                float v = acc[m][n][r] + bv;
                if (VARIANT == 1) v = fmaxf(v, 0.f);
                Cb[(size_t)mm * Nc + nn] = f2bf(v);
            }
        }
    }
}

// ---------------------------------------------------------------------------
// K-half GEMM for 128x128 grid-capped shapes (out-proj, FFN2): 8 waves as
// 2Mx2Nx2K, BK=64, ring-4 (128 KB), counted vmcnt, A-frag register prefetch.
// wk=1 partials reduced into wk=0 via LDS at end. (Unchanged from round 5.)
// Output: f32 = acc + bias + res (res may alias Cout elementwise).
// Requires M%128==0, Nc%128==0, K%128==0, K/64 >= 4, grid%8==0.
// ---------------------------------------------------------------------------
__global__ __launch_bounds__(512, 2) void gemm_kh_kernel(
    const unsigned short* __restrict__ A,
    const unsigned short* __restrict__ W,
    const float* __restrict__ bias,
    const float* res, float* Cout, int Nc, int K) {
    __shared__ unsigned short smem[4][16384];   // 4 x (128+128) rows x 64 x 2B

    const int tid  = threadIdx.x;
    const int lane = tid & 63;
    const int wv   = tid >> 6;
    const int wk   = wv >> 2;          // K-half
    const int wm   = (wv >> 1) & 1;    // M-half
    const int wn   = wv & 1;           // N-half

    int bx = blockIdx.x, by = blockIdx.y;
    {   // bijective XCD chunk swizzle (grid %8 == 0)
        const int gx  = gridDim.x;
        const int nwg = gx * gridDim.y;
        const int lin = by * gx + bx;
        const int sl  = (lin & 7) * (nwg >> 3) + (lin >> 3);
        bx = sl % gx; by = sl / gx;
    }
    const int row0 = by * 128;
    const int col0 = bx * 128;
    const int NT   = K >> 6;

    const int srow = lane >> 3;
    const int sq   = ((lane & 7) ^ ((lane >> 3) & 7)) * 8;   // elems
    const unsigned short* Ag = A + (size_t)(row0 + srow) * K + sq;
    const unsigned short* Wg = W + (size_t)(col0 + srow) * K + sq;

    auto stage = [&](int t) {
        unsigned short* dst = &smem[t & 3][0];
#pragma unroll
        for (int s = 0; s < 2; ++s) {
            const int r = (wv + s * 8) * 8;
            __builtin_amdgcn_global_load_lds(
                (const __attribute__((address_space(1))) unsigned int*)(Ag + (size_t)r * K + t * 64),
                (__attribute__((address_space(3))) unsigned int*)(dst + r * 64), 16, 0, 0);
        }
#pragma unroll
        for (int s = 0; s < 2; ++s) {
            const int r = (wv + s * 8) * 8;
            __builtin_amdgcn_global_load_lds(
                (const __attribute__((address_space(1))) unsigned int*)(Wg + (size_t)r * K + t * 64),
                (__attribute__((address_space(3))) unsigned int*)(dst + 8192 + r * 64), 16, 0, 0);
        }
    };

    const int frow = lane & 15;
    const int quad = lane >> 4;
    const int phys = ((wk * 4 + quad) ^ (frow & 7)) * 8;     // elems
    const int abase = (wm * 64 + frow) * 64 + phys;
    const int bbase = 8192 + (wn * 64 + frow) * 64 + phys;

    floatx4 acc[4][4];
#pragma unroll
    for (int m = 0; m < 4; ++m)
#pragma unroll
        for (int n = 0; n < 4; ++n) acc[m][n] = (floatx4){0.f, 0.f, 0.f, 0.f};

    bf16x8 afA[4], afB[4];

    stage(0); stage(1); stage(2);
    SWAIT("vmcnt(8)");
    __builtin_amdgcn_s_barrier();
    SCHEDBAR();
#pragma unroll
    for (int m = 0; m < 4; ++m)
        afA[m] = *(const bf16x8*)(&smem[0][0] + abase + m * 1024);

#define KH_BODY(T, AFC, AFN, TAIL)                                             \
    {                                                                          \
        const int t_ = (T);                                                    \
        if (!(TAIL)) vm_wait_rt<2>(NT - 2 - t_);                               \
        __builtin_amdgcn_s_barrier();                                          \
        SCHEDBAR();                                                            \
        if (t_ + 3 < NT) stage(t_ + 3);                                        \
        const unsigned short* buf_ = &smem[t_ & 3][0];                         \
        bf16x8 bfr0 = *(const bf16x8*)(buf_ + bbase);                          \
        bf16x8 bfr1 = *(const bf16x8*)(buf_ + bbase + 1024);                   \
        SCHEDBAR();                                                            \
        bf16x8 bfr2 = *(const bf16x8*)(buf_ + bbase + 2048);                   \
        bf16x8 bfr3 = *(const bf16x8*)(buf_ + bbase + 3072);                   \
        if (!(TAIL)) {                                                         \
            const unsigned short* nbuf_ = &smem[(t_ + 1) & 3][0];              \
            _Pragma("unroll")                                                  \
            for (int m = 0; m < 4; ++m)                                        \
                AFN[m] = *(const bf16x8*)(nbuf_ + abase + m * 1024);           \
        }                                                                      \
        SCHEDBAR();                                                            \
        if (TAIL) { SWAIT("lgkmcnt(2)"); } else { SWAIT("lgkmcnt(6)"); }       \
        SCHEDBAR();                                                            \
        __builtin_amdgcn_s_setprio(1);                                         \
        _Pragma("unroll")                                                      \
        for (int m = 0; m < 4; ++m) {                                          \
            acc[m][0] = __builtin_amdgcn_mfma_f32_16x16x32_bf16(               \
                AFC[m], bfr0, acc[m][0], 0, 0, 0);                             \
            acc[m][1] = __builtin_amdgcn_mfma_f32_16x16x32_bf16(               \
                AFC[m], bfr1, acc[m][1], 0, 0, 0);                             \
        }                                                                      \
        SCHEDBAR();                                                            \
        if (TAIL) { SWAIT("lgkmcnt(0)"); } else { SWAIT("lgkmcnt(4)"); }       \
        SCHEDBAR();                                                            \
        _Pragma("unroll")                                                      \
        for (int m = 0; m < 4; ++m) {                                          \
            acc[m][2] = __builtin_amdgcn_mfma_f32_16x16x32_bf16(               \
                AFC[m], bfr2, acc[m][2], 0, 0, 0);                             \
            acc[m][3] = __builtin_amdgcn_mfma_f32_16x16x32_bf16(               \
                AFC[m], bfr3, acc[m][3], 0, 0, 0);                             \
        }                                                                      \
        __builtin_amdgcn_s_setprio(0);                                         \
        SCHEDBAR();                                                            \
    }

    int t = 0;
    for (; t < NT - 2; t += 2) {
        KH_BODY(t,     afA, afB, false);
        KH_BODY(t + 1, afB, afA, false);
    }
    KH_BODY(NT - 2, afA, afB, false);
    KH_BODY(NT - 1, afB, afA, true);
#undef KH_BODY

    // cross-K reduction: wk=1 partials -> LDS -> wk=0 adds
    __syncthreads();
    float* pbuf = (float*)&smem[0][0];
    const int pair = wm * 2 + wn;
    if (wk == 1) {
#pragma unroll
        for (int m = 0; m < 4; ++m)
#pragma unroll
            for (int n = 0; n < 4; ++n)
                *(floatx4*)&pbuf[pair * 4096 + (m * 4 + n) * 256 + lane * 4] = acc[m][n];
    }
    __syncthreads();
    if (wk == 0) {
        const int crow = (lane >> 4) * 4;
        const int ccol = lane & 15;
#pragma unroll
        for (int n = 0; n < 4; ++n) {
            const int nn = col0 + wn * 64 + n * 16 + ccol;
            const float bv = bias[nn];
#pragma unroll
            for (int m = 0; m < 4; ++m) {
                floatx4 p = *(const floatx4*)&pbuf[pair * 4096 + (m * 4 + n) * 256 + lane * 4];
#pragma unroll
                for (int r = 0; r < 4; ++r) {
                    const int mm = row0 + wm * 64 + m * 16 + crow + r;
                    Cout[(size_t)mm * Nc + nn] =
                        acc[m][n][r] + p[r] + bv + res[(size_t)mm * Nc + nn];
                }
            }
        }
    }
}

// ---------------------------------------------------------------------------
// Flash-style MFMA attention (unchanged). rel_bias finite only for
// 0 <= i-j < 512. One block = 64 Q rows for (b,h); 4 waves; online softmax.
// ---------------------------------------------------------------------------
__global__ __launch_bounds__(256) void attn_mfma_kernel(
    const unsigned short* __restrict__ qkv,
    const float* __restrict__ rel_pos,
    unsigned short* __restrict__ o) {
    __shared__ unsigned short K_s[2][64][32];     // 8 KB
    __shared__ unsigned short V_s[64][72];        // 9 KB  [d][key]
    __shared__ unsigned short P_s[4][2][16][32];  // 8 KB  per-wave
    __shared__ float rel_s[MAXLEN];               // 2 KB

    const int qt = blockIdx.x, h = blockIdx.y, b = blockIdx.z;
    const int q0 = qt * 64;
    const int tid  = threadIdx.x;
    const int lane = tid & 63;
    const int w    = tid >> 6;
    const int quad = lane >> 4;
    const int c15  = lane & 15;

    rel_s[tid]       = rel_pos[h * MAXLEN + tid];
    rel_s[tid + 256] = rel_pos[h * MAXLEN + tid + 256];

    const size_t rowstride = 3 * EE;
    const size_t base_q = (size_t)(b * NN) * rowstride + h * DD;
    const size_t base_k = base_q + EE;
    const size_t base_v = base_q + 2 * EE;

    bf16x8 aq[2];
    {
        const unsigned short* qrow =
            qkv + base_q + (size_t)(q0 + w * 16 + c15) * rowstride + quad * 8;
        aq[0] = *(const bf16x8*)(qrow);
        aq[1] = *(const bf16x8*)(qrow + 32);
    }

    floatx4 Oacc[4];
#pragma unroll
    for (int j = 0; j < 4; ++j) Oacc[j] = (floatx4){0.f, 0.f, 0.f, 0.f};
    float m_r[4], l_r[4];
#pragma unroll
    for (int r = 0; r < 4; ++r) { m_r[r] = -1e30f; l_r[r] = 0.f; }

    const int jlo = max(0, q0 - (MAXLEN - 1));
    const int c0 = jlo >> 6;
    const int c1 = (q0 + 63) >> 6;

    for (int cc = c0; cc <= c1; ++cc) {
        const int jb0 = cc << 6;
        __syncthreads();

        {
            const int krow = w * 16 + (lane >> 2);
            const int dofs = (lane & 3) * 8;
            const unsigned short* gk =
                qkv + base_k + (size_t)(jb0 + krow) * rowstride + dofs;
            __builtin_amdgcn_global_load_lds(
                (const __attribute__((address_space(1))) unsigned int*)gk,
                (__attribute__((address_space(3))) unsigned int*)&K_s[0][w * 16][0],
                16, 0, 0);
            __builtin_amdgcn_global_load_lds(
                (const __attribute__((address_space(1))) unsigned int*)(gk + 32),
                (__attribute__((address_space(3))) unsigned int*)&K_s[1][w * 16][0],
                16, 0, 0);
        }
        {
            const int key = lane;
            const int d0  = w * 16;
            const unsigned short* gv =
                qkv + base_v + (size_t)(jb0 + key) * rowstride + d0;
            ushort8 va = *(const ushort8*)(gv);
            ushort8 vb = *(const ushort8*)(gv + 8);
#pragma unroll
            for (int ii = 0; ii < 8; ++ii) V_s[d0 + ii][key] = va[ii];
#pragma unroll
            for (int ii = 0; ii < 8; ++ii) V_s[d0 + 8 + ii][key] = vb[ii];
        }
        __syncthreads();

        floatx4 S[4];
#pragma unroll
        for (int jb = 0; jb < 4; ++jb) {
            S[jb] = (floatx4){0.f, 0.f, 0.f, 0.f};
            bf16x8 bk0 = *(const bf16x8*)&K_s[0][jb * 16 + c15][quad * 8];
            bf16x8 bk1 = *(const bf16x8*)&K_s[1][jb * 16 + c15][quad * 8];
            S[jb] = __builtin_amdgcn_mfma_f32_16x16x32_bf16(aq[0], bk0, S[jb], 0, 0, 0);
            S[jb] = __builtin_amdgcn_mfma_f32_16x16x32_bf16(aq[1], bk1, S[jb], 0, 0, 0);
        }

        const int i_base = q0 + w * 16 + quad * 4;
        float sv[4][4];
        float mc[4] = {-1e30f, -1e30f, -1e30f, -1e30f};
#pragma unroll
        for (int jb = 0; jb < 4; ++jb) {
            const int jg = jb0 + jb * 16 + c15;
#pragma unroll
            for (int r = 0; r < 4; ++r) {
                const int rel = (i_base + r) - jg;
                float s;
                if (rel >= 0 && rel < MAXLEN) s = S[jb][r] * 0.125f + rel_s[rel];
                else                          s = -1e30f;
                sv[jb][r] = s;
                mc[r] = fmaxf(mc[r], s);
            }
        }
#pragma unroll
        for (int off = 1; off < 16; off <<= 1)
#pragma unroll
            for (int r = 0; r < 4; ++r) mc[r] = fmaxf(mc[r], __shfl_xor(mc[r], off));

        float alpha[4], psum[4];
#pragma unroll
        for (int r = 0; r < 4; ++r) {
            const float mn = fmaxf(m_r[r], mc[r]);
            alpha[r] = __expf(m_r[r] - mn);
            m_r[r] = mn;
            psum[r] = 0.f;
        }
#pragma unroll
        for (int jb = 0; jb < 4; ++jb)
#pragma unroll
            for (int r = 0; r < 4; ++r) {
                const float p = __expf(sv[jb][r] - m_r[r]);
                sv[jb][r] = p;
                psum[r] += p;
            }
#pragma unroll
        for (int off = 1; off < 16; off <<= 1)
#pragma unroll
            for (int r = 0; r < 4; ++r) psum[r] += __shfl_xor(psum[r], off);
#pragma unroll
        for (int r = 0; r < 4; ++r) l_r[r] = l_r[r] * alpha[r] + psum[r];
#pragma unroll
        for (int jb = 0; jb < 4; ++jb)
#pragma unroll
            for (int r = 0; r < 4; ++r) Oacc[jb][r] *= alpha[r];

#pragma unroll
        for (int jb = 0; jb < 4; ++jb)
#pragma unroll
            for (int r = 0; r < 4; ++r)
                P_s[w][jb >> 1][quad * 4 + r][(jb & 1) * 16 + c15] = f2bf(sv[jb][r]);

        bf16x8 ap0 = *(const bf16x8*)&P_s[w][0][c15][quad * 8];
        bf16x8 ap1 = *(const bf16x8*)&P_s[w][1][c15][quad * 8];

#pragma unroll
        for (int jd = 0; jd < 4; ++jd) {
            bf16x8 bv0 = *(const bf16x8*)&V_s[jd * 16 + c15][quad * 8];
            bf16x8 bv1 = *(const bf16x8*)&V_s[jd * 16 + c15][32 + quad * 8];
            Oacc[jd] = __builtin_amdgcn_mfma_f32_16x16x32_bf16(ap0, bv0, Oacc[jd], 0, 0, 0);
            Oacc[jd] = __builtin_amdgcn_mfma_f32_16x16x32_bf16(ap1, bv1, Oacc[jd], 0, 0, 0);
        }
    }

    float inv[4];
#pragma unroll
    for (int r = 0; r < 4; ++r) inv[r] = 1.0f / l_r[r];
#pragma unroll
    for (int jd = 0; jd < 4; ++jd) {
#pragma unroll
        for (int r = 0; r < 4; ++r) {
            const int row = q0 + w * 16 + quad * 4 + r;
            const int col = h * DD + jd * 16 + c15;
            o[(size_t)(b * NN + row) * EE + col] = f2bf(Oacc[jd][r] * inv[r]);
        }
    }
}

// ---------------------------------------------------------------------------
// Launch
// ---------------------------------------------------------------------------
extern "C" void kernel_launch(void* const* d_in, const int* in_sizes, int n_in,
                              void* d_out, int out_size, void* d_ws, size_t ws_size,
                              hipStream_t stream) {
    const float* x         = (const float*)d_in[0];
    const float* rel_pos   = (const float*)d_in[1];
    const float* in_proj_w = (const float*)d_in[2];
    const float* in_proj_b = (const float*)d_in[3];
    const float* out_w     = (const float*)d_in[4];
    const float* out_b     = (const float*)d_in[5];
    const float* w1        = (const float*)d_in[6];
    const float* b1        = (const float*)d_in[7];
    const float* w2        = (const float*)d_in[8];
    const float* b2        = (const float*)d_in[9];
    const float* ln1_g     = (const float*)d_in[10];
    const float* ln1_b     = (const float*)d_in[11];
    const float* ln2_g     = (const float*)d_in[12];
    const float* ln2_b     = (const float*)d_in[13];
    float* out = (float*)d_out;

    char* wsb = (char*)d_ws;
    const size_t MB = 1024 * 1024;
    unsigned short* wqkv_b = (unsigned short*)(wsb + 0);        // 6 MB
    unsigned short* wout_b = (unsigned short*)(wsb + 6 * MB);   // 2 MB
    unsigned short* w1_b   = (unsigned short*)(wsb + 8 * MB);   // 8 MB
    unsigned short* w2_b   = (unsigned short*)(wsb + 16 * MB);  // 8 MB
    unsigned short* xn_b   = (unsigned short*)(wsb + 24 * MB);  // 8 MB (xn, then xm)
    unsigned short* qkv_b  = (unsigned short*)(wsb + 32 * MB);  // 24 MB
    unsigned short* h_b    = (unsigned short*)(wsb + 32 * MB);  // 32 MB (reuses qkv+o)
    unsigned short* o_b    = (unsigned short*)(wsb + 56 * MB);  // 8 MB

    const int Mrows = BB * NN;   // 4096

    // all four weight conversions in one launch (3145728 float4s)
    f2bf_all_kernel<<<3 * EE * EE / 256, 256, 0, stream>>>(
        in_proj_w, out_w, w1, w2, wqkv_b, wout_b, w1_b, w2_b);

    ln_kernel<<<Mrows, 256, 0, stream>>>(x, ln1_g, ln1_b, xn_b);
    // QKV: 128^2 TLP kernel, grid 24x32 = 768 blocks (3/CU, 12 waves/CU)
    gemm97t_kernel<0><<<dim3(3 * EE / 128, Mrows / 128), 256, 0, stream>>>(
        xn_b, wqkv_b, in_proj_b, qkv_b, 3 * EE, EE);
    attn_mfma_kernel<<<dim3(NN / 64, HH, BB), 256, 0, stream>>>(qkv_b, rel_pos, o_b);
    // out-proj + residual: K-half kernel (grid-capped 8x32 = 256 blocks)
    gemm_kh_kernel<<<dim3(EE / 128, Mrows / 128), 512, 0, stream>>>(
        o_b, wout_b, out_b, x, out, EE, EE);
    ln_kernel<<<Mrows, 256, 0, stream>>>(out, ln2_g, ln2_b, xn_b);
    // FFN1: 128^2 TLP kernel, grid 32x32 = 1024 blocks (3/CU resident), relu
    gemm97t_kernel<1><<<dim3(4 * EE / 128, Mrows / 128), 256, 0, stream>>>(
        xn_b, w1_b, b1, h_b, 4 * EE, EE);
    // FFN2 + residual (in-place on d_out): K-half kernel, grid 8x32
    gemm_kh_kernel<<<dim3(EE / 128, Mrows / 128), 512, 0, stream>>>(
        h_b, w2_b, b2, out, out, EE, 4 * EE);
}